// Round 1
// baseline (904.716 us; speedup 1.0000x reference)
//
#include <hip/hip_runtime.h>

#define THREADS 256

// ---------------- degree count ----------------
__global__ void count_deg(const int* __restrict__ eu, const int* __restrict__ ei,
                          int* __restrict__ du, int* __restrict__ di, int E) {
    int stride = gridDim.x * blockDim.x;
    for (int e = blockIdx.x * blockDim.x + threadIdx.x; e < E; e += stride) {
        atomicAdd(&du[eu[e]], 1);
        atomicAdd(&di[ei[e]], 1);
    }
}

// ---------------- single-block exclusive scan (n up to ~100k) ----------------
__global__ void scan_excl(const int* __restrict__ deg, int* __restrict__ off, int n) {
    __shared__ int sh[1024];
    int tid = threadIdx.x;
    int chunk = (n + 1023) >> 10;
    int start = tid * chunk;
    int end = min(start + chunk, n);
    int s = 0;
    for (int j = start; j < end; ++j) s += deg[j];
    sh[tid] = s;
    __syncthreads();
    for (int ofs = 1; ofs < 1024; ofs <<= 1) {
        int t = (tid >= ofs) ? sh[tid - ofs] : 0;
        __syncthreads();
        sh[tid] += t;
        __syncthreads();
    }
    int base = (tid > 0) ? sh[tid - 1] : 0;
    for (int j = start; j < end; ++j) { off[j] = base; base += deg[j]; }
    if (tid == 1023) off[n] = sh[1023];
}

// ---------------- CSR fill (both directions), w computed here ----------------
__global__ void fill_csr(const int* __restrict__ eu, const int* __restrict__ ei,
                         const int* __restrict__ du, const int* __restrict__ di,
                         const int* __restrict__ offu, const int* __restrict__ offi,
                         int* __restrict__ curu, int* __restrict__ curi,
                         int2* __restrict__ entu, int2* __restrict__ enti, int E) {
    int stride = gridDim.x * blockDim.x;
    for (int e = blockIdx.x * blockDim.x + threadIdx.x; e < E; e += stride) {
        int u = eu[e], i = ei[e];
        float w = rsqrtf(fmaxf((float)du[u] * (float)di[i], 1.0f));
        int wb = __float_as_int(w);
        int su = atomicAdd(&curu[u], 1);
        entu[offu[u] + su] = make_int2(i, wb);
        int si = atomicAdd(&curi[i], 1);
        enti[offi[i] + si] = make_int2(u, wb);
    }
}

// ---------------- one propagation layer: gather-based, 16 lanes per node ----------------
__global__ void prop(const float* __restrict__ xu, const float* __restrict__ xi,
                     const int* __restrict__ offu, const int* __restrict__ offi,
                     const int2* __restrict__ entu, const int2* __restrict__ enti,
                     float* __restrict__ y, int nU, int N) {
    int node = blockIdx.x * (blockDim.x >> 4) + (threadIdx.x >> 4);
    int t = threadIdx.x & 15;
    if (node >= N) return;
    const int2* ent;
    const float* src;
    int beg, end;
    if (node < nU) {
        beg = offu[node]; end = offu[node + 1]; ent = entu; src = xi;
    } else {
        int i = node - nU;
        beg = offi[i]; end = offi[i + 1]; ent = enti; src = xu;
    }
    float4 acc = make_float4(0.f, 0.f, 0.f, 0.f);
    for (int k = beg; k < end; ++k) {
        int2 e = ent[k];
        float w = __int_as_float(e.y);
        float4 v = *reinterpret_cast<const float4*>(src + (size_t)e.x * 64 + t * 4);
        acc.x += w * v.x; acc.y += w * v.y; acc.z += w * v.z; acc.w += w * v.w;
    }
    *reinterpret_cast<float4*>(y + (size_t)node * 64 + t * 4) = acc;
}

// ---------------- accumulate selected rows (users/pos/neg) ----------------
__global__ void sel_accum(const float* __restrict__ ubase, const float* __restrict__ ibase,
                          const int* __restrict__ users, const int* __restrict__ pos,
                          const int* __restrict__ neg,
                          float* __restrict__ sel, int B, int add) {
    int r = blockIdx.x * (blockDim.x >> 4) + (threadIdx.x >> 4);
    int t = threadIdx.x & 15;
    if (r >= 3 * B) return;
    int which = r / B, b = r - which * B;
    const float* base;
    int idx;
    if (which == 0)      { base = ubase; idx = users[b]; }
    else if (which == 1) { base = ibase; idx = pos[b]; }
    else                 { base = ibase; idx = neg[b]; }
    float4 v = *reinterpret_cast<const float4*>(base + (size_t)idx * 64 + t * 4);
    float4* dst = reinterpret_cast<float4*>(sel + (size_t)r * 64 + t * 4);
    if (add) {
        float4 d = *dst;
        d.x += v.x; d.y += v.y; d.z += v.z; d.w += v.w;
        *dst = d;
    } else {
        *dst = v;
    }
}

// ---------------- final scores: one wave per b ----------------
__global__ void score(const float* __restrict__ sel, float* __restrict__ out, int B) {
    int b = blockIdx.x * (blockDim.x >> 6) + (threadIdx.x >> 6);
    int lane = threadIdx.x & 63;
    if (b >= B) return;
    float u = sel[(size_t)b * 64 + lane];
    float p = sel[(size_t)(B + b) * 64 + lane];
    float n = sel[(size_t)(2 * B + b) * 64 + lane];
    float ps = u * p, ns = u * n;
    for (int ofs = 32; ofs; ofs >>= 1) {
        ps += __shfl_down(ps, ofs);
        ns += __shfl_down(ns, ofs);
    }
    if (lane == 0) {
        out[b]     = ps * (1.0f / 16.0f);  // (acc/4)·(acc/4)
        out[B + b] = ns * (1.0f / 16.0f);
    }
}

// ---------------- regularization loss ----------------
__global__ void regk(const float* __restrict__ ut, const float* __restrict__ it,
                     const int* __restrict__ users, const int* __restrict__ pos,
                     const int* __restrict__ neg,
                     float* __restrict__ out_reg, int B, float scale) {
    int total = 3 * B * 64;
    float s = 0.f;
    int stride = gridDim.x * blockDim.x;
    for (int idx = blockIdx.x * blockDim.x + threadIdx.x; idx < total; idx += stride) {
        int r = idx >> 6, d = idx & 63;
        int which = r / B, b = r - which * B;
        float v;
        if (which == 0)      v = ut[(size_t)users[b] * 64 + d];
        else if (which == 1) v = it[(size_t)pos[b] * 64 + d];
        else                 v = it[(size_t)neg[b] * 64 + d];
        s += v * v;
    }
    for (int ofs = 32; ofs; ofs >>= 1) s += __shfl_down(s, ofs);
    __shared__ float sh[4];
    int lane = threadIdx.x & 63, wid = threadIdx.x >> 6;
    if (lane == 0) sh[wid] = s;
    __syncthreads();
    if (threadIdx.x == 0) {
        float tot = 0.f;
        for (int i = 0; i < (int)(blockDim.x >> 6); ++i) tot += sh[i];
        atomicAdd(out_reg, tot * scale);
    }
}

extern "C" void kernel_launch(void* const* d_in, const int* in_sizes, int n_in,
                              void* d_out, int out_size, void* d_ws, size_t ws_size,
                              hipStream_t stream) {
    const float* ut   = (const float*)d_in[0];
    const float* it   = (const float*)d_in[1];
    const int* eu     = (const int*)d_in[2];
    const int* ei     = (const int*)d_in[3];
    const int* users  = (const int*)d_in[4];
    const int* pos    = (const int*)d_in[5];
    const int* neg    = (const int*)d_in[6];
    int nU = in_sizes[0] / 64;
    int nI = in_sizes[1] / 64;
    int E  = in_sizes[2];
    int B  = in_sizes[4];
    int N  = nU + nI;
    float* out = (float*)d_out;

    // workspace carve-out (256B aligned)
    char* ws = (char*)d_ws;
    size_t cursor = 0;
    auto alloc = [&](size_t bytes) -> void* {
        cursor = (cursor + 255) & ~(size_t)255;
        void* p = ws + cursor;
        cursor += bytes;
        return p;
    };
    int*  du   = (int*)alloc((size_t)nU * 4);
    int*  di   = (int*)alloc((size_t)nI * 4);
    int*  curu = (int*)alloc((size_t)nU * 4);
    int*  curi = (int*)alloc((size_t)nI * 4);
    size_t zero_span = cursor;  // du..curi zeroed in one memset
    int*  offu = (int*)alloc((size_t)(nU + 1) * 4);
    int*  offi = (int*)alloc((size_t)(nI + 1) * 4);
    int2* entu = (int2*)alloc((size_t)E * 8);
    int2* enti = (int2*)alloc((size_t)E * 8);
    float* bufA = (float*)alloc((size_t)N * 64 * 4);
    float* bufB = (float*)alloc((size_t)N * 64 * 4);
    float* sel  = (float*)alloc((size_t)3 * B * 64 * 4);

    hipMemsetAsync(d_ws, 0, zero_span, stream);
    hipMemsetAsync(out + 2 * B, 0, sizeof(float), stream);

    // 1. degrees
    int gridE = (E + THREADS - 1) / THREADS;
    count_deg<<<gridE, THREADS, 0, stream>>>(eu, ei, du, di, E);

    // 2. exclusive scans
    scan_excl<<<1, 1024, 0, stream>>>(du, offu, nU);
    scan_excl<<<1, 1024, 0, stream>>>(di, offi, nI);

    // 3. CSR fill (computes per-edge w)
    fill_csr<<<gridE, THREADS, 0, stream>>>(eu, ei, du, di, offu, offi, curu, curi, entu, enti, E);

    // 4. layer-0 selected rows
    int gridSel = (3 * B + 15) / 16;
    sel_accum<<<gridSel, THREADS, 0, stream>>>(ut, it, users, pos, neg, sel, B, 0);

    // 5. three propagation layers + selected accumulation
    int gridProp = (N + 15) / 16;
    const size_t urows = (size_t)nU * 64;
    // layer 1: tables -> bufA
    prop<<<gridProp, THREADS, 0, stream>>>(ut, it, offu, offi, entu, enti, bufA, nU, N);
    sel_accum<<<gridSel, THREADS, 0, stream>>>(bufA, bufA + urows, users, pos, neg, sel, B, 1);
    // layer 2: bufA -> bufB
    prop<<<gridProp, THREADS, 0, stream>>>(bufA, bufA + urows, offu, offi, entu, enti, bufB, nU, N);
    sel_accum<<<gridSel, THREADS, 0, stream>>>(bufB, bufB + urows, users, pos, neg, sel, B, 1);
    // layer 3: bufB -> bufA
    prop<<<gridProp, THREADS, 0, stream>>>(bufB, bufB + urows, offu, offi, entu, enti, bufA, nU, N);
    sel_accum<<<gridSel, THREADS, 0, stream>>>(bufA, bufA + urows, users, pos, neg, sel, B, 1);

    // 6. scores
    int gridScore = (B + 3) / 4;
    score<<<gridScore, THREADS, 0, stream>>>(sel, out, B);

    // 7. regularization
    regk<<<256, THREADS, 0, stream>>>(ut, it, users, pos, neg, out + 2 * B, B, 1e-4f / (float)B);
}

// Round 2
// 687.644 us; speedup vs baseline: 1.3157x; 1.3157x over previous
//
#include <hip/hip_runtime.h>

#define THREADS 256

// ---------------- degree count ----------------
__global__ void count_deg(const int* __restrict__ eu, const int* __restrict__ ei,
                          int* __restrict__ du, int* __restrict__ di, int E) {
    int stride = gridDim.x * blockDim.x;
    for (int e = blockIdx.x * blockDim.x + threadIdx.x; e < E; e += stride) {
        atomicAdd(&du[eu[e]], 1);
        atomicAdd(&di[ei[e]], 1);
    }
}

// ---------------- segment assignment: off[node] = contiguous segment start ----------------
// Node order in the entry array is irrelevant; only per-node contiguity matters.
// Wave-level inclusive scan of degrees + one atomicAdd per wave on a global cursor.
__global__ void assign_off(const int* __restrict__ deg, int* __restrict__ off,
                           int* __restrict__ cursor, int n) {
    int idx = blockIdx.x * blockDim.x + threadIdx.x;
    int lane = threadIdx.x & 63;
    int d = (idx < n) ? deg[idx] : 0;
    int s = d;
    #pragma unroll
    for (int ofs = 1; ofs < 64; ofs <<= 1) {
        int t = __shfl_up(s, ofs);
        if (lane >= ofs) s += t;
    }
    int total = __shfl(s, 63);
    int base = 0;
    if (lane == 63) base = atomicAdd(cursor, total);
    base = __shfl(base, 63);
    if (idx < n) off[idx] = base + s - d;
}

// ---------------- CSR fill (both directions), w computed here ----------------
__global__ void fill_csr(const int* __restrict__ eu, const int* __restrict__ ei,
                         const int* __restrict__ du, const int* __restrict__ di,
                         const int* __restrict__ offu, const int* __restrict__ offi,
                         int* __restrict__ curu, int* __restrict__ curi,
                         int2* __restrict__ entu, int2* __restrict__ enti, int E) {
    int stride = gridDim.x * blockDim.x;
    for (int e = blockIdx.x * blockDim.x + threadIdx.x; e < E; e += stride) {
        int u = eu[e], i = ei[e];
        float w = rsqrtf(fmaxf((float)du[u] * (float)di[i], 1.0f));
        int wb = __float_as_int(w);
        int su = atomicAdd(&curu[u], 1);
        entu[offu[u] + su] = make_int2(i, wb);
        int si = atomicAdd(&curi[i], 1);
        enti[offi[i] + si] = make_int2(u, wb);
    }
}

// ---------------- one propagation layer: gather-based, 16 lanes per node ----------------
__global__ void prop(const float* __restrict__ xu, const float* __restrict__ xi,
                     const int* __restrict__ offu, const int* __restrict__ offi,
                     const int* __restrict__ du, const int* __restrict__ di,
                     const int2* __restrict__ entu, const int2* __restrict__ enti,
                     float* __restrict__ y, int nU, int N) {
    int node = blockIdx.x * (blockDim.x >> 4) + (threadIdx.x >> 4);
    int t = threadIdx.x & 15;
    if (node >= N) return;
    const int2* ent;
    const float* src;
    int beg, end;
    if (node < nU) {
        beg = offu[node]; end = beg + du[node]; ent = entu; src = xi;
    } else {
        int i = node - nU;
        beg = offi[i]; end = beg + di[i]; ent = enti; src = xu;
    }
    float4 acc = make_float4(0.f, 0.f, 0.f, 0.f);
    for (int k = beg; k < end; ++k) {
        int2 e = ent[k];
        float w = __int_as_float(e.y);
        float4 v = *reinterpret_cast<const float4*>(src + (size_t)e.x * 64 + t * 4);
        acc.x += w * v.x; acc.y += w * v.y; acc.z += w * v.z; acc.w += w * v.w;
    }
    *reinterpret_cast<float4*>(y + (size_t)node * 64 + t * 4) = acc;
}

// ---------------- accumulate selected rows (users/pos/neg) ----------------
__global__ void sel_accum(const float* __restrict__ ubase, const float* __restrict__ ibase,
                          const int* __restrict__ users, const int* __restrict__ pos,
                          const int* __restrict__ neg,
                          float* __restrict__ sel, int B, int add) {
    int r = blockIdx.x * (blockDim.x >> 4) + (threadIdx.x >> 4);
    int t = threadIdx.x & 15;
    if (r >= 3 * B) return;
    int which = r / B, b = r - which * B;
    const float* base;
    int idx;
    if (which == 0)      { base = ubase; idx = users[b]; }
    else if (which == 1) { base = ibase; idx = pos[b]; }
    else                 { base = ibase; idx = neg[b]; }
    float4 v = *reinterpret_cast<const float4*>(base + (size_t)idx * 64 + t * 4);
    float4* dst = reinterpret_cast<float4*>(sel + (size_t)r * 64 + t * 4);
    if (add) {
        float4 d = *dst;
        d.x += v.x; d.y += v.y; d.z += v.z; d.w += v.w;
        *dst = d;
    } else {
        *dst = v;
    }
}

// ---------------- final scores: one wave per b ----------------
__global__ void score(const float* __restrict__ sel, float* __restrict__ out, int B) {
    int b = blockIdx.x * (blockDim.x >> 6) + (threadIdx.x >> 6);
    int lane = threadIdx.x & 63;
    if (b >= B) return;
    float u = sel[(size_t)b * 64 + lane];
    float p = sel[(size_t)(B + b) * 64 + lane];
    float n = sel[(size_t)(2 * B + b) * 64 + lane];
    float ps = u * p, ns = u * n;
    for (int ofs = 32; ofs; ofs >>= 1) {
        ps += __shfl_down(ps, ofs);
        ns += __shfl_down(ns, ofs);
    }
    if (lane == 0) {
        out[b]     = ps * (1.0f / 16.0f);  // (acc/4)·(acc/4)
        out[B + b] = ns * (1.0f / 16.0f);
    }
}

// ---------------- regularization loss ----------------
__global__ void regk(const float* __restrict__ ut, const float* __restrict__ it,
                     const int* __restrict__ users, const int* __restrict__ pos,
                     const int* __restrict__ neg,
                     float* __restrict__ out_reg, int B, float scale) {
    int total = 3 * B * 64;
    float s = 0.f;
    int stride = gridDim.x * blockDim.x;
    for (int idx = blockIdx.x * blockDim.x + threadIdx.x; idx < total; idx += stride) {
        int r = idx >> 6, d = idx & 63;
        int which = r / B, b = r - which * B;
        float v;
        if (which == 0)      v = ut[(size_t)users[b] * 64 + d];
        else if (which == 1) v = it[(size_t)pos[b] * 64 + d];
        else                 v = it[(size_t)neg[b] * 64 + d];
        s += v * v;
    }
    for (int ofs = 32; ofs; ofs >>= 1) s += __shfl_down(s, ofs);
    __shared__ float sh[4];
    int lane = threadIdx.x & 63, wid = threadIdx.x >> 6;
    if (lane == 0) sh[wid] = s;
    __syncthreads();
    if (threadIdx.x == 0) {
        float tot = 0.f;
        for (int i = 0; i < (int)(blockDim.x >> 6); ++i) tot += sh[i];
        atomicAdd(out_reg, tot * scale);
    }
}

extern "C" void kernel_launch(void* const* d_in, const int* in_sizes, int n_in,
                              void* d_out, int out_size, void* d_ws, size_t ws_size,
                              hipStream_t stream) {
    const float* ut   = (const float*)d_in[0];
    const float* it   = (const float*)d_in[1];
    const int* eu     = (const int*)d_in[2];
    const int* ei     = (const int*)d_in[3];
    const int* users  = (const int*)d_in[4];
    const int* pos    = (const int*)d_in[5];
    const int* neg    = (const int*)d_in[6];
    int nU = in_sizes[0] / 64;
    int nI = in_sizes[1] / 64;
    int E  = in_sizes[2];
    int B  = in_sizes[4];
    int N  = nU + nI;
    float* out = (float*)d_out;

    // workspace carve-out (256B aligned)
    char* ws = (char*)d_ws;
    size_t cursor = 0;
    auto alloc = [&](size_t bytes) -> void* {
        cursor = (cursor + 255) & ~(size_t)255;
        void* p = ws + cursor;
        cursor += bytes;
        return p;
    };
    int*  du   = (int*)alloc((size_t)nU * 4);
    int*  di   = (int*)alloc((size_t)nI * 4);
    int*  curu = (int*)alloc((size_t)nU * 4);
    int*  curi = (int*)alloc((size_t)nI * 4);
    int*  curs = (int*)alloc(2 * 4);          // segment cursors for entu / enti
    size_t zero_span = cursor;                // du..curs zeroed in one memset
    int*  offu = (int*)alloc((size_t)nU * 4);
    int*  offi = (int*)alloc((size_t)nI * 4);
    int2* entu = (int2*)alloc((size_t)E * 8);
    int2* enti = (int2*)alloc((size_t)E * 8);
    float* bufA = (float*)alloc((size_t)N * 64 * 4);
    float* bufB = (float*)alloc((size_t)N * 64 * 4);
    float* sel  = (float*)alloc((size_t)3 * B * 64 * 4);

    hipMemsetAsync(d_ws, 0, zero_span, stream);
    hipMemsetAsync(out + 2 * B, 0, sizeof(float), stream);

    // 1. degrees
    int gridE = (E + THREADS - 1) / THREADS;
    count_deg<<<gridE, THREADS, 0, stream>>>(eu, ei, du, di, E);

    // 2. segment assignment (replaces full exclusive scans)
    assign_off<<<(nU + THREADS - 1) / THREADS, THREADS, 0, stream>>>(du, offu, curs, nU);
    assign_off<<<(nI + THREADS - 1) / THREADS, THREADS, 0, stream>>>(di, offi, curs + 1, nI);

    // 3. CSR fill (computes per-edge w)
    fill_csr<<<gridE, THREADS, 0, stream>>>(eu, ei, du, di, offu, offi, curu, curi, entu, enti, E);

    // 4. layer-0 selected rows
    int gridSel = (3 * B + 15) / 16;
    sel_accum<<<gridSel, THREADS, 0, stream>>>(ut, it, users, pos, neg, sel, B, 0);

    // 5. three propagation layers + selected accumulation
    int gridProp = (N + 15) / 16;
    const size_t urows = (size_t)nU * 64;
    // layer 1: tables -> bufA
    prop<<<gridProp, THREADS, 0, stream>>>(ut, it, offu, offi, du, di, entu, enti, bufA, nU, N);
    sel_accum<<<gridSel, THREADS, 0, stream>>>(bufA, bufA + urows, users, pos, neg, sel, B, 1);
    // layer 2: bufA -> bufB
    prop<<<gridProp, THREADS, 0, stream>>>(bufA, bufA + urows, offu, offi, du, di, entu, enti, bufB, nU, N);
    sel_accum<<<gridSel, THREADS, 0, stream>>>(bufB, bufB + urows, users, pos, neg, sel, B, 1);
    // layer 3: bufB -> bufA
    prop<<<gridProp, THREADS, 0, stream>>>(bufB, bufB + urows, offu, offi, du, di, entu, enti, bufA, nU, N);
    sel_accum<<<gridSel, THREADS, 0, stream>>>(bufA, bufA + urows, users, pos, neg, sel, B, 1);

    // 6. scores
    int gridScore = (B + 3) / 4;
    score<<<gridScore, THREADS, 0, stream>>>(sel, out, B);

    // 7. regularization
    regk<<<256, THREADS, 0, stream>>>(ut, it, users, pos, neg, out + 2 * B, B, 1e-4f / (float)B);
}